// Round 8
// baseline (962.490 us; speedup 1.0000x reference)
//
#include <hip/hip_runtime.h>

// RNN_64072322122514: B=4096, T=2048, F=8, H=32, O=8 Elman RNN, all fp32 I/O.
//   h_t = tanh(x_t @ W_ih^T + b_ih + b_hh + h_{t-1} @ W_hh^T);  y = h_T @ W_out^T + b_out
//
// R7 post-mortem: VALU-issue-bound. R7's 4-way split raised occupancy to 34%
// but added 34% total VALU work (butterfly/overhead x16 thin waves) -> no gain
// over R6 (430 us). Objective = total instr-cyc per CU-step. R8:
//   - R6's efficient full-dot structure (2 rows/wave, 32 lanes/row, lane owns
//     ONE h-dim with the full 32-k dot -> NO reduce), but h NEVER touches LDS:
//     the all-gather is 32 independent ds_swizzle broadcasts (BitMode
//     offset=j<<5: new_lane=j within each 32-lane group = the row) straight
//     from the h register. One pipelined LDS-crossbar latency per step vs
//     R6's two serial ones (write->b128 read + swizzle reduce).
//   - dots in fp32 v_fma, 4 independent accumulators (fdot2 would need a
//     pack step that re-inserts a serial swizzle; same instr count anyway).
//   - xp FMAs from prefetched x regs (independent of swizzles - fill the
//     swizzle shadow). A/B group prefetch with asm memory-clobber pinning.
//   - weights pre-scaled by 2*log2e; tanh = 1 - 2*rcp(exp2(s)+1).
//   - 2048 waves = 2 waves/SIMD; issue ~236 VALU-cyc/SIMD-step vs chain ~155
//     -> issue-bound ~240-300 cyc/SIMD-step, predicted 210-270 us hot.

static constexpr int T_STEPS = 2048;
static constexpr int FDIM    = 8;
static constexpr int HDIM    = 32;
static constexpr int ODIM    = 8;
static constexpr int ROWS_PER_BLOCK = 8;    // 4 waves x 2 rows
static constexpr int GROUP   = 4;           // steps per prefetch group
static constexpr int NGROUP  = T_STEPS / GROUP;   // 512 (even)

__global__ __launch_bounds__(256, 2) void rnn_scan_kernel(
    const float* __restrict__ x,      // [B, T, F]
    const float* __restrict__ W_ih,   // [H, F]
    const float* __restrict__ W_hh,   // [H, H]
    const float* __restrict__ b_ih,   // [H]
    const float* __restrict__ b_hh,   // [H]
    const float* __restrict__ W_out,  // [O, H]
    const float* __restrict__ b_out,  // [O]
    float* __restrict__ out)          // [1, B, O]
{
    const float K = 2.8853900817779268f;  // 2*log2(e)
    const int tid  = threadIdx.x;
    const int lane = tid & 63;
    const int wave = tid >> 6;
    const int q    = lane & 31;           // h-dim owned by this lane
    const int sub  = lane >> 5;           // which of the wave's 2 rows
    const int r    = wave * 2 + sub;      // row within block
    const long long b = (long long)blockIdx.x * ROWS_PER_BLOCK + r;

    __shared__ float hsh[ROWS_PER_BLOCK][HDIM];   // epilogue only (1 KB)

    // ---- resident weights (fp32, pre-scaled by K) ----
    float wh[HDIM];
#pragma unroll
    for (int j = 0; j < HDIM; ++j) wh[j] = W_hh[q * HDIM + j] * K;
    float wi[FDIM];
#pragma unroll
    for (int f = 0; f < FDIM; ++f) wi[f] = W_ih[q * FDIM + f] * K;
    const float bias = (b_ih[q] + b_hh[q]) * K;

    const float4* xq = reinterpret_cast<const float4*>(x + (size_t)b * T_STEPS * FDIM);
    float h = 0.0f;

#define LOADG(buf, gi)                                                         \
    {                                                                          \
        const int base = (gi) * (2 * GROUP);                                   \
        _Pragma("unroll")                                                      \
        for (int k = 0; k < 2 * GROUP; ++k) buf[k] = xq[base + k];             \
    }                                                                          \
    asm volatile("" ::: "memory");

    // broadcast lane j's h to all lanes of its 32-lane group (the row)
#define SWZ(j) const float g##j = __int_as_float(                              \
        __builtin_amdgcn_ds_swizzle(__float_as_int(h), ((j) << 5)));

#define STEP(xa, xb)                                                           \
    {                                                                          \
        SWZ(0)  SWZ(1)  SWZ(2)  SWZ(3)  SWZ(4)  SWZ(5)  SWZ(6)  SWZ(7)         \
        SWZ(8)  SWZ(9)  SWZ(10) SWZ(11) SWZ(12) SWZ(13) SWZ(14) SWZ(15)        \
        SWZ(16) SWZ(17) SWZ(18) SWZ(19) SWZ(20) SWZ(21) SWZ(22) SWZ(23)        \
        SWZ(24) SWZ(25) SWZ(26) SWZ(27) SWZ(28) SWZ(29) SWZ(30) SWZ(31)        \
        /* xp: independent of the swizzles - fills their latency shadow */     \
        float a0 = bias, a1 = 0.0f, a2 = 0.0f, a3 = 0.0f;                      \
        a0 = fmaf(wi[0], xa.x, a0);  a1 = fmaf(wi[1], xa.y, a1);               \
        a2 = fmaf(wi[2], xa.z, a2);  a3 = fmaf(wi[3], xa.w, a3);               \
        a0 = fmaf(wi[4], xb.x, a0);  a1 = fmaf(wi[5], xb.y, a1);               \
        a2 = fmaf(wi[6], xb.z, a2);  a3 = fmaf(wi[7], xb.w, a3);               \
        a0 = fmaf(wh[0],  g0,  a0);  a1 = fmaf(wh[1],  g1,  a1);               \
        a2 = fmaf(wh[2],  g2,  a2);  a3 = fmaf(wh[3],  g3,  a3);               \
        a0 = fmaf(wh[4],  g4,  a0);  a1 = fmaf(wh[5],  g5,  a1);               \
        a2 = fmaf(wh[6],  g6,  a2);  a3 = fmaf(wh[7],  g7,  a3);               \
        a0 = fmaf(wh[8],  g8,  a0);  a1 = fmaf(wh[9],  g9,  a1);               \
        a2 = fmaf(wh[10], g10, a2);  a3 = fmaf(wh[11], g11, a3);               \
        a0 = fmaf(wh[12], g12, a0);  a1 = fmaf(wh[13], g13, a1);               \
        a2 = fmaf(wh[14], g14, a2);  a3 = fmaf(wh[15], g15, a3);               \
        a0 = fmaf(wh[16], g16, a0);  a1 = fmaf(wh[17], g17, a1);               \
        a2 = fmaf(wh[18], g18, a2);  a3 = fmaf(wh[19], g19, a3);               \
        a0 = fmaf(wh[20], g20, a0);  a1 = fmaf(wh[21], g21, a1);               \
        a2 = fmaf(wh[22], g22, a2);  a3 = fmaf(wh[23], g23, a3);               \
        a0 = fmaf(wh[24], g24, a0);  a1 = fmaf(wh[25], g25, a1);               \
        a2 = fmaf(wh[26], g26, a2);  a3 = fmaf(wh[27], g27, a3);               \
        a0 = fmaf(wh[28], g28, a0);  a1 = fmaf(wh[29], g29, a1);               \
        a2 = fmaf(wh[30], g30, a2);  a3 = fmaf(wh[31], g31, a3);               \
        const float s = (a0 + a1) + (a2 + a3);                                 \
        const float e = __builtin_amdgcn_exp2f(s);                             \
        const float rc = __builtin_amdgcn_rcpf(e + 1.0f);                      \
        h = fmaf(-2.0f, rc, 1.0f);                                             \
    }

#define STEPS(buf)                                                             \
    STEP(buf[0], buf[1]) STEP(buf[2], buf[3])                                  \
    STEP(buf[4], buf[5]) STEP(buf[6], buf[7])

    float4 bufA[2 * GROUP], bufB[2 * GROUP];
    LOADG(bufA, 0)

    for (int gi = 0; gi < NGROUP; gi += 2) {
        const int g1 = (gi + 1 < NGROUP) ? (gi + 1) : gi;
        LOADG(bufB, g1)
        STEPS(bufA)
        const int g2 = (gi + 2 < NGROUP) ? (gi + 2) : gi;
        LOADG(bufA, g2)
        STEPS(bufB)
    }
#undef STEPS
#undef STEP
#undef SWZ
#undef LOADG

    // ---- epilogue: y = h_T @ W_out^T + b_out ----
    hsh[r][q] = h;
    __syncthreads();
    if (tid < ROWS_PER_BLOCK * ODIM) {   // 64 threads
        const int rr = tid >> 3;
        const int o  = tid & 7;
        float acc = b_out[o];
#pragma unroll
        for (int j = 0; j < HDIM; ++j)
            acc = fmaf(hsh[rr][j], W_out[o * HDIM + j], acc);
        out[((long long)blockIdx.x * ROWS_PER_BLOCK + rr) * ODIM + o] = acc;
    }
}

extern "C" void kernel_launch(void* const* d_in, const int* in_sizes, int n_in,
                              void* d_out, int out_size, void* d_ws, size_t ws_size,
                              hipStream_t stream) {
    const float* x     = (const float*)d_in[0];
    const float* W_ih  = (const float*)d_in[1];
    const float* W_hh  = (const float*)d_in[2];
    const float* b_ih  = (const float*)d_in[3];
    const float* b_hh  = (const float*)d_in[4];
    const float* W_out = (const float*)d_in[5];
    const float* b_out = (const float*)d_in[6];

    const int B = in_sizes[0] / (T_STEPS * FDIM);   // 4096
    const int grid = B / ROWS_PER_BLOCK;            // 512 blocks = 2/CU

    rnn_scan_kernel<<<grid, 256, 0, stream>>>(
        x, W_ih, W_hh, b_ih, b_hh, W_out, b_out, (float*)d_out);
}